// Round 1
// baseline (341.618 us; speedup 1.0000x reference)
//
#include <hip/hip_runtime.h>
#include <hip/hip_bf16.h>

#define BATCH 8
#define CCH 1024
#define NHW 4096
#define SCALE 5.0f   // 1/TEMPERATURE
#define ROWS (BATCH * CCH)

typedef unsigned short u16;
typedef __attribute__((ext_vector_type(8))) short short8;
typedef __attribute__((ext_vector_type(4))) float float4v;

__device__ __forceinline__ void async_load16(const void* gsrc, void* ldst) {
    __builtin_amdgcn_global_load_lds(
        (__attribute__((address_space(1))) void*)gsrc,
        (__attribute__((address_space(3))) void*)ldst,
        16, 0, 0);
}

__device__ __forceinline__ u16 f2bf(float f) {
    union { float f; unsigned int u; } c; c.f = f;
    unsigned int u = c.u;
    unsigned int r = u + 0x7FFFu + ((u >> 16) & 1u);
    return (u16)(r >> 16);
}

// One block per row: diag = sum(x^2)*SCALE, zero l_acc, optionally convert to bf16.
template <bool CONVERT>
__global__ __launch_bounds__(256) void prep_kernel(const float* __restrict__ x,
                                                   u16* __restrict__ xbf,
                                                   float* __restrict__ diag,
                                                   float* __restrict__ l_acc) {
    const int row = blockIdx.x;          // 0..8191
    const int tid = threadIdx.x;
    const float* src = x + (size_t)row * NHW;
    float ssum = 0.f;
#pragma unroll
    for (int p = 0; p < 4; ++p) {
        const int idx = p * 1024 + tid * 4;
        float4 v = *(const float4*)(src + idx);
        ssum += v.x * v.x + v.y * v.y + v.z * v.z + v.w * v.w;
        if (CONVERT) {
            ushort4 o;
            o.x = f2bf(v.x); o.y = f2bf(v.y); o.z = f2bf(v.z); o.w = f2bf(v.w);
            *(ushort4*)(xbf + (size_t)row * NHW + idx) = o;
        }
    }
#pragma unroll
    for (int m = 1; m < 64; m <<= 1) ssum += __shfl_xor(ssum, m);
    __shared__ float red[4];
    if ((tid & 63) == 0) red[tid >> 6] = ssum;
    __syncthreads();
    if (tid == 0) {
        diag[row] = (red[0] + red[1] + red[2] + red[3]) * SCALE;
        l_acc[row] = 0.f;
    }
}

// Gram tile kernel: 128x128 tile per block over K=4096, bf16 MFMA.
// LDS layout: chunk-major — 16B chunk (kc, r) at offset (kc*128 + r)*16B.
template <bool BF16SRC>
__global__ __launch_bounds__(256) void gram_kernel(const u16* __restrict__ Xbf,
                                                   const float* __restrict__ Xf,
                                                   const float* __restrict__ diag,
                                                   float* __restrict__ l_acc,
                                                   float* __restrict__ num) {
    __shared__ __align__(16) u16 As[8192];   // 8 kchunks * 128 rows * 8 bf16 = 16KB
    __shared__ __align__(16) u16 Bs[8192];

    const int bid = blockIdx.x;
    const int b  = bid & 7;          // batch in low bits -> XCD spread heuristic
    const int t2 = bid >> 3;
    const int bi = t2 >> 3;          // row block 0..7
    const int bj = t2 & 7;           // col block 0..7

    const int tid  = threadIdx.x;
    const int lane = tid & 63;
    const int w    = tid >> 6;       // wave 0..3
    const int wm   = w >> 1;         // wave row 0..1
    const int wn   = w & 1;          // wave col 0..1

    // staging mapping: chunk c = t*256 + tid ; r = tid&127 ; kc = (tid>>7) + 2*t
    const int r_st  = tid & 127;
    const int kc0   = tid >> 7;      // 0 or 1

    const u16*   pA  = nullptr; const u16*   pB  = nullptr;
    const float* pAf = nullptr; const float* pBf = nullptr;
    if (BF16SRC) {
        const u16* baseX = Xbf + (size_t)b * CCH * NHW;
        pA = baseX + (size_t)(bi * 128 + r_st) * NHW + kc0 * 8;
        pB = baseX + (size_t)(bj * 128 + r_st) * NHW + kc0 * 8;
    } else {
        const float* baseXf = Xf + (size_t)b * CCH * NHW;
        pAf = baseXf + (size_t)(bi * 128 + r_st) * NHW + kc0 * 8;
        pBf = baseXf + (size_t)(bj * 128 + r_st) * NHW + kc0 * 8;
    }

    float4v acc[4][4] = {};

    for (int K0 = 0; K0 < NHW; K0 += 64) {
        __syncthreads();   // previous iter's LDS reads complete
        if (BF16SRC) {
#pragma unroll
            for (int t = 0; t < 4; ++t) {
                async_load16(pA + t * 16, As + (size_t)(t * 256 + w * 64) * 8);
                async_load16(pB + t * 16, Bs + (size_t)(t * 256 + w * 64) * 8);
            }
            pA += 64; pB += 64;
        } else {
#pragma unroll
            for (int t = 0; t < 4; ++t) {
                const int c = t * 256 + tid;  // LDS chunk index
                {
                    float4 f0 = *(const float4*)(pAf + t * 16);
                    float4 f1 = *(const float4*)(pAf + t * 16 + 4);
                    u16* d = As + (size_t)c * 8;
                    d[0]=f2bf(f0.x); d[1]=f2bf(f0.y); d[2]=f2bf(f0.z); d[3]=f2bf(f0.w);
                    d[4]=f2bf(f1.x); d[5]=f2bf(f1.y); d[6]=f2bf(f1.z); d[7]=f2bf(f1.w);
                }
                {
                    float4 f0 = *(const float4*)(pBf + t * 16);
                    float4 f1 = *(const float4*)(pBf + t * 16 + 4);
                    u16* d = Bs + (size_t)c * 8;
                    d[0]=f2bf(f0.x); d[1]=f2bf(f0.y); d[2]=f2bf(f0.z); d[3]=f2bf(f0.w);
                    d[4]=f2bf(f1.x); d[5]=f2bf(f1.y); d[6]=f2bf(f1.z); d[7]=f2bf(f1.w);
                }
            }
            pAf += 64; pBf += 64;
        }
        __syncthreads();   // staging visible (drains vmcnt before barrier)

#pragma unroll
        for (int ks = 0; ks < 2; ++ks) {
            short8 af[4], bf[4];
            const int kq = ks * 4 + (lane >> 4);   // kchunk 0..7
            const int rl = lane & 15;
#pragma unroll
            for (int mt = 0; mt < 4; ++mt)
                af[mt] = *(const short8*)(As + (size_t)((kq * 128) + wm * 64 + mt * 16 + rl) * 8);
#pragma unroll
            for (int nt = 0; nt < 4; ++nt)
                bf[nt] = *(const short8*)(Bs + (size_t)((kq * 128) + wn * 64 + nt * 16 + rl) * 8);
#pragma unroll
            for (int mt = 0; mt < 4; ++mt)
#pragma unroll
                for (int nt = 0; nt < 4; ++nt)
                    acc[mt][nt] = __builtin_amdgcn_mfma_f32_16x16x32_bf16(af[mt], bf[nt], acc[mt][nt], 0, 0, 0);
        }
    }

    // Epilogue: v = acc*SCALE - diag[row]; e = exp(v); row-sum over this wave's
    // 64 columns; atomicAdd into l_acc. Diagonal element also stored to num.
    const int q  = lane >> 4;    // quad 0..3
    const int cl = lane & 15;    // col within 16
    const int rowbase = bi * 128 + wm * 64;
    const bool diagblock = (bi == bj) && (wm == wn);

#pragma unroll
    for (int mt = 0; mt < 4; ++mt) {
#pragma unroll
        for (int reg = 0; reg < 4; ++reg) {
            const int row = rowbase + mt * 16 + q * 4 + reg;
            const float dg = diag[b * CCH + row];
            float s = 0.f;
#pragma unroll
            for (int nt = 0; nt < 4; ++nt) {
                const float v = acc[mt][nt][reg] * SCALE - dg;
                const float e = __expf(v);
                s += e;
                if (diagblock && (mt == nt) && (cl == q * 4 + reg)) {
                    num[b * CCH + row] = e;
                }
            }
            s += __shfl_xor(s, 1);
            s += __shfl_xor(s, 2);
            s += __shfl_xor(s, 4);
            s += __shfl_xor(s, 8);
            if (cl == 0) atomicAdd(l_acc + b * CCH + row, s);
        }
    }
}

__global__ __launch_bounds__(256) void finalize_kernel(const float* __restrict__ l_acc,
                                                       const float* __restrict__ num,
                                                       float* __restrict__ out) {
    const int tid = threadIdx.x;
    float s = 0.f;
    for (int r = tid; r < ROWS; r += 256) {
        const float d = num[r] / l_acc[r];
        s += -__logf(d + 1e-10f);
    }
#pragma unroll
    for (int m = 1; m < 64; m <<= 1) s += __shfl_xor(s, m);
    __shared__ float red[4];
    if ((tid & 63) == 0) red[tid >> 6] = s;
    __syncthreads();
    if (tid == 0) out[0] = (red[0] + red[1] + red[2] + red[3]) * (1.0f / (float)ROWS);
}

extern "C" void kernel_launch(void* const* d_in, const int* in_sizes, int n_in,
                              void* d_out, int out_size, void* d_ws, size_t ws_size,
                              hipStream_t stream) {
    const float* x = (const float*)d_in[0];
    float* out = (float*)d_out;

    const size_t xbf_bytes  = (size_t)BATCH * CCH * NHW * 2;  // 67108864
    const size_t stat_bytes = (size_t)ROWS * 4;               // 32768
    const bool fast = ws_size >= xbf_bytes + 3 * stat_bytes;

    if (fast) {
        u16*   xbf   = (u16*)d_ws;
        float* diag  = (float*)((char*)d_ws + xbf_bytes);
        float* l_acc = diag + ROWS;
        float* num   = l_acc + ROWS;
        prep_kernel<true><<<ROWS, 256, 0, stream>>>(x, xbf, diag, l_acc);
        gram_kernel<true><<<BATCH * 8 * 8, 256, 0, stream>>>(xbf, nullptr, diag, l_acc, num);
        finalize_kernel<<<1, 256, 0, stream>>>(l_acc, num, out);
    } else {
        float* diag  = (float*)d_ws;
        float* l_acc = diag + ROWS;
        float* num   = l_acc + ROWS;
        prep_kernel<false><<<ROWS, 256, 0, stream>>>(x, nullptr, diag, l_acc);
        gram_kernel<false><<<BATCH * 8 * 8, 256, 0, stream>>>(nullptr, x, diag, l_acc, num);
        finalize_kernel<<<1, 256, 0, stream>>>(l_acc, num, out);
    }
}